// Round 1
// baseline (191.459 us; speedup 1.0000x reference)
//
#include <hip/hip_runtime.h>
#include <stdint.h>

#define NH 16
#define SEQ 2048
#define DMODEL 1024
#define HD 64
#define NBATCH 2
#define MTOT (NBATCH * SEQ)              // 4096 rows for the big GEMMs
#define QSCALE 0.17677669529663687f      // 1/sqrt(B*H) = 1/sqrt(32)  (faithful bug)

typedef __bf16 bf16x8 __attribute__((ext_vector_type(8)));
typedef float f32x4 __attribute__((ext_vector_type(4)));

// round-to-nearest-even fp32 -> bf16 bit pattern
__device__ __forceinline__ unsigned short bf16u(float x) {
  unsigned u = __builtin_bit_cast(unsigned, x);
  u += 0x7fffu + ((u >> 16) & 1u);
  return (unsigned short)(u >> 16);
}

__device__ __forceinline__ f32x4 mfma16(bf16x8 a, bf16x8 b, f32x4 c) {
  return __builtin_amdgcn_mfma_f32_16x16x32_bf16(a, b, c, 0, 0, 0);
}

__device__ __forceinline__ void gl16(const void* g, void* l) {
  __builtin_amdgcn_global_load_lds(
      (const __attribute__((address_space(1))) void*)g,
      (__attribute__((address_space(3))) void*)l, 16, 0, 0);
}

// ---- cast fp32 -> bf16 for queries/keys/values (each 4096x1024) ----
__global__ __launch_bounds__(256) void cast_x_kernel(
    const float* __restrict__ x0, const float* __restrict__ x1,
    const float* __restrict__ x2, unsigned short* __restrict__ o0,
    unsigned short* __restrict__ o1, unsigned short* __restrict__ o2) {
  const float* src = (blockIdx.y == 0) ? x0 : (blockIdx.y == 1) ? x1 : x2;
  unsigned short* dst = (blockIdx.y == 0) ? o0 : (blockIdx.y == 1) ? o1 : o2;
  const int n4 = MTOT * DMODEL / 4;
  for (int i = blockIdx.x * blockDim.x + threadIdx.x; i < n4;
       i += gridDim.x * blockDim.x) {
    float4 f = reinterpret_cast<const float4*>(src)[i];
    ushort4 u;
    u.x = bf16u(f.x); u.y = bf16u(f.y); u.z = bf16u(f.z); u.w = bf16u(f.w);
    reinterpret_cast<ushort4*>(dst)[i] = u;
  }
}

// ---- transpose + cast W (1024x1024 fp32 stored (K,N)) -> Wt bf16 (N,K) ----
__global__ __launch_bounds__(256) void transpose_w_kernel(
    const float* __restrict__ w0, const float* __restrict__ w1,
    const float* __restrict__ w2, const float* __restrict__ w3,
    unsigned short* __restrict__ t0, unsigned short* __restrict__ t1,
    unsigned short* __restrict__ t2, unsigned short* __restrict__ t3) {
  __shared__ float tile[64][65];   // +1 pad: conflict-free column reads
  const float* w = (blockIdx.z == 0) ? w0 : (blockIdx.z == 1) ? w1
                   : (blockIdx.z == 2) ? w2 : w3;
  unsigned short* t = (blockIdx.z == 0) ? t0 : (blockIdx.z == 1) ? t1
                      : (blockIdx.z == 2) ? t2 : t3;
  int k0 = blockIdx.y * 64, n0 = blockIdx.x * 64;
  int tx = threadIdx.x & 63, ty = threadIdx.x >> 6;
#pragma unroll
  for (int i = 0; i < 16; ++i) {
    int kk = ty * 16 + i;
    tile[kk][tx] = w[(k0 + kk) * DMODEL + n0 + tx];   // coalesced read
  }
  __syncthreads();
#pragma unroll
  for (int i = 0; i < 16; ++i) {
    int nn = ty * 16 + i;
    t[(n0 + nn) * DMODEL + k0 + tx] = bf16u(tile[tx][nn]);  // coalesced write
  }
}

// ---- 128x128-tile bf16 GEMM, K=1024, N=1024.  C = A(M,K) @ Wt(N,K)^T ----
// mode 0: out bf16, head-split (B,H,S,hd)   (for q, k)
// mode 1: out bf16, head-split transposed (B,H,hd,S)  (for v)
// mode 2: out fp32, plain row-major (M,N)   (final projection)
__global__ __launch_bounds__(256) void gemm128_kernel(
    const unsigned short* __restrict__ A, const unsigned short* __restrict__ Wt,
    unsigned short* __restrict__ outb, float* __restrict__ outf, int mode) {
  __shared__ unsigned short lA[128 * 32];
  __shared__ unsigned short lB[128 * 32];
  const int tid = threadIdx.x;
  const int lane = tid & 63, wid = tid >> 6;
  const int wr = wid >> 1, wc = wid & 1;
  const int m0 = blockIdx.x * 128, n0 = blockIdx.y * 128;
  const int lm = lane & 15, lg = lane >> 4;
  const int lk = lg * 8;

  f32x4 acc[4][4] = {};

  for (int kt = 0; kt < DMODEL / 32; ++kt) {
#pragma unroll
    for (int i = 0; i < 2; ++i) {
      int c = tid + i * 256;                 // 0..511 16B chunks
      int row = c >> 2, cb = c & 3;
      gl16(A + (m0 + row) * DMODEL + kt * 32 + cb * 8, (char*)lA + c * 16);
      gl16(Wt + (n0 + row) * DMODEL + kt * 32 + cb * 8, (char*)lB + c * 16);
    }
    __syncthreads();   // drains vmcnt(0): staging complete

    bf16x8 af[4], bfr[4];
#pragma unroll
    for (int x = 0; x < 4; ++x) {
      af[x] = *reinterpret_cast<const bf16x8*>(&lA[(wr * 64 + x * 16 + lm) * 32 + lk]);
      bfr[x] = *reinterpret_cast<const bf16x8*>(&lB[(wc * 64 + x * 16 + lm) * 32 + lk]);
    }
#pragma unroll
    for (int mi = 0; mi < 4; ++mi)
#pragma unroll
      for (int ni = 0; ni < 4; ++ni)
        acc[mi][ni] = mfma16(af[mi], bfr[ni], acc[mi][ni]);
    __syncthreads();   // all reads done before next staging
  }

  // epilogue.  C/D layout: col = lane&15, row = (lane>>4)*4 + r
#pragma unroll
  for (int mi = 0; mi < 4; ++mi) {
#pragma unroll
    for (int ni = 0; ni < 4; ++ni) {
      int col = n0 + wc * 64 + ni * 16 + lm;
#pragma unroll
      for (int r = 0; r < 4; ++r) {
        int row = m0 + wr * 64 + mi * 16 + lg * 4 + r;
        float v = acc[mi][ni][r];
        if (mode == 2) {
          outf[row * DMODEL + col] = v;
        } else {
          int b = row >> 11, s = row & (SEQ - 1);
          int h = col >> 6, d = col & (HD - 1);
          int idx = (mode == 0) ? (((b * NH + h) * SEQ + s) * HD + d)
                                : (((b * NH + h) * HD + d) * SEQ + s);
          outb[idx] = bf16u(v);
        }
      }
    }
  }
}

// ---- flash attention: 64 q-rows per block, K/V tiles of 64 keys ----
// qb, kb: (B,H,S,64) bf16;  vt: (B,H,64,S) bf16;  ao: (B,S,1024) bf16
__global__ __launch_bounds__(256) void attn_kernel(
    const unsigned short* __restrict__ qb, const unsigned short* __restrict__ kb,
    const unsigned short* __restrict__ vt, const int* __restrict__ vlens,
    unsigned short* __restrict__ ao) {
  __shared__ unsigned short lK[64 * 64];   // [key][d], rows XOR-swizzled
  __shared__ unsigned short lV[64 * 64];   // [d][key], rows XOR-swizzled
  __shared__ unsigned short lP[4 * 16 * 64]; // per-wave P[q][key], swizzled
  const int tid = threadIdx.x;
  const int lane = tid & 63, w = tid >> 6;
  const int bh = blockIdx.y, b = bh >> 4, h = bh & 15;
  const int s0 = blockIdx.x * 64;
  const int vlen = vlens[b];
  const int nkt = (vlen + 63) >> 6;
  const int lm = lane & 15, lg = lane >> 4;

  // Q fragments straight from global: row = s0 + w*16 + lm, k-elems contiguous
  const unsigned short* qrow = qb + (bh * SEQ + s0 + w * 16 + lm) * HD;
  bf16x8 qf0 = *reinterpret_cast<const bf16x8*>(qrow + lg * 8);
  bf16x8 qf1 = *reinterpret_cast<const bf16x8*>(qrow + 32 + lg * 8);

  f32x4 oacc[4] = {};
  float mrow[4] = {-3e38f, -3e38f, -3e38f, -3e38f};
  float lrow[4] = {0.f, 0.f, 0.f, 0.f};

  for (int kt = 0; kt < nkt; ++kt) {
    const int k0 = kt * 64;
    // stage K and V tiles; source column pre-swizzled so linear LDS dest
    // + swizzled ds_read gives conflict-free b128 reads (T2 / m173 pattern)
#pragma unroll
    for (int i = 0; i < 2; ++i) {
      int c = tid + i * 256;                // 0..511
      int row = c >> 3, pcol = c & 7;
      int scol = pcol ^ (row & 7);
      gl16(kb + (bh * SEQ + k0 + row) * HD + scol * 8, (char*)lK + c * 16);
      gl16(vt + (bh * HD + row) * SEQ + k0 + scol * 8, (char*)lV + c * 16);
    }
    __syncthreads();

    // S = Q K^T   (A=Q 16x32, B=K^T: col=key, k=d)
    f32x4 sa[4];
#pragma unroll
    for (int nb = 0; nb < 4; ++nb) {
      int krow = nb * 16 + lm;
      const char* base = (const char*)lK + krow * 128;
      int sw = (krow & 7) << 4;
      bf16x8 kf0 = *reinterpret_cast<const bf16x8*>(base + ((lg * 16) ^ sw));
      bf16x8 kf1 = *reinterpret_cast<const bf16x8*>(base + ((64 + lg * 16) ^ sw));
      f32x4 z = {};
      z = mfma16(qf0, kf0, z);
      z = mfma16(qf1, kf1, z);
      sa[nb] = z;
    }

    const bool last = (kt == nkt - 1);
    float pr[4][4];
#pragma unroll
    for (int r = 0; r < 4; ++r) {
      float s[4];
#pragma unroll
      for (int nb = 0; nb < 4; ++nb) {
        int key = k0 + nb * 16 + lm;
        float val = sa[nb][r] * QSCALE;
        if (last && key >= vlen) val = -1000000.0f;   // MASK_VALUE
        s[nb] = val;
      }
      float tmax = fmaxf(fmaxf(s[0], s[1]), fmaxf(s[2], s[3]));
#pragma unroll
      for (int off = 1; off < 16; off <<= 1)
        tmax = fmaxf(tmax, __shfl_xor(tmax, off, 64));
      float nm = fmaxf(mrow[r], tmax);
      float sf = __expf(mrow[r] - nm);
      mrow[r] = nm;
      float psum = 0.f;
#pragma unroll
      for (int nb = 0; nb < 4; ++nb) {
        float p = __expf(s[nb] - nm);
        pr[nb][r] = p;
        psum += p;
      }
#pragma unroll
      for (int off = 1; off < 16; off <<= 1)
        psum += __shfl_xor(psum, off, 64);
      lrow[r] = lrow[r] * sf + psum;
#pragma unroll
      for (int nb = 0; nb < 4; ++nb) oacc[nb][r] *= sf;
    }

    // write P (bf16) to per-wave LDS region, swizzled, then transpose-read
#pragma unroll
    for (int r = 0; r < 4; ++r) {
      int q = lg * 4 + r;
      char* pb = (char*)lP + w * 2048 + q * 128;
      int sw = (q & 7) << 4;
#pragma unroll
      for (int nb = 0; nb < 4; ++nb) {
        int kcol = nb * 16 + lm;
        *reinterpret_cast<unsigned short*>(pb + ((kcol * 2) ^ sw)) = bf16u(pr[nb][r]);
      }
    }
    __syncthreads();   // P visible (and lgkm drained) before A-frag reads

    // O += P V   (A=P 16x32: row=q, k=key;  B=V: col=d, k=key)
    const char* pbase = (const char*)lP + w * 2048 + lm * 128;
    int psw = (lm & 7) << 4;
    bf16x8 pf0 = *reinterpret_cast<const bf16x8*>(pbase + ((lg * 16) ^ psw));
    bf16x8 pf1 = *reinterpret_cast<const bf16x8*>(pbase + ((64 + lg * 16) ^ psw));
#pragma unroll
    for (int nb = 0; nb < 4; ++nb) {
      int vrow = nb * 16 + lm;
      const char* vbase = (const char*)lV + vrow * 128;
      int vsw = (vrow & 7) << 4;
      bf16x8 vf0 = *reinterpret_cast<const bf16x8*>(vbase + ((lg * 16) ^ vsw));
      bf16x8 vf1 = *reinterpret_cast<const bf16x8*>(vbase + ((64 + lg * 16) ^ vsw));
      oacc[nb] = mfma16(pf0, vf0, oacc[nb]);
      oacc[nb] = mfma16(pf1, vf1, oacc[nb]);
    }
    __syncthreads();   // lK/lV reads done before next staging
  }

  float inv[4];
#pragma unroll
  for (int r = 0; r < 4; ++r) inv[r] = 1.0f / lrow[r];
#pragma unroll
  for (int nb = 0; nb < 4; ++nb) {
    int d = nb * 16 + lm;
#pragma unroll
    for (int r = 0; r < 4; ++r) {
      int q = s0 + w * 16 + lg * 4 + r;
      ao[(b * SEQ + q) * DMODEL + h * HD + d] = bf16u(oacc[nb][r] * inv[r]);
    }
  }
}

extern "C" void kernel_launch(void* const* d_in, const int* in_sizes, int n_in,
                              void* d_out, int out_size, void* d_ws, size_t ws_size,
                              hipStream_t stream) {
  (void)in_sizes; (void)n_in; (void)out_size; (void)ws_size;
  const float* q = (const float*)d_in[0];
  const float* k = (const float*)d_in[1];
  const float* v = (const float*)d_in[2];
  const int* vlens = (const int*)d_in[3];
  const float* Wq = (const float*)d_in[4];
  const float* Wk = (const float*)d_in[5];
  const float* Wv = (const float*)d_in[6];
  const float* Wo = (const float*)d_in[7];
  float* out = (float*)d_out;

  char* ws = (char*)d_ws;
  const size_t MB = 1u << 20;
  unsigned short* xq = (unsigned short*)(ws + 0 * MB);   // 8 MB each
  unsigned short* xk = (unsigned short*)(ws + 8 * MB);
  unsigned short* xv = (unsigned short*)(ws + 16 * MB);
  unsigned short* wqt = (unsigned short*)(ws + 24 * MB); // 2 MB each
  unsigned short* wkt = (unsigned short*)(ws + 26 * MB);
  unsigned short* wvt = (unsigned short*)(ws + 28 * MB);
  unsigned short* wot = (unsigned short*)(ws + 30 * MB);
  unsigned short* qb = (unsigned short*)(ws + 32 * MB);  // 8 MB each
  unsigned short* kb = (unsigned short*)(ws + 40 * MB);
  unsigned short* vt = (unsigned short*)(ws + 48 * MB);
  unsigned short* ao = (unsigned short*)(ws + 56 * MB);

  cast_x_kernel<<<dim3(512, 3), 256, 0, stream>>>(q, k, v, xq, xk, xv);
  transpose_w_kernel<<<dim3(16, 16, 4), 256, 0, stream>>>(Wq, Wk, Wv, Wo,
                                                          wqt, wkt, wvt, wot);
  gemm128_kernel<<<dim3(32, 8), 256, 0, stream>>>(xq, wqt, qb, nullptr, 0);
  gemm128_kernel<<<dim3(32, 8), 256, 0, stream>>>(xk, wkt, kb, nullptr, 0);
  gemm128_kernel<<<dim3(32, 8), 256, 0, stream>>>(xv, wvt, vt, nullptr, 1);
  attn_kernel<<<dim3(SEQ / 64, NBATCH * NH), 256, 0, stream>>>(qb, kb, vt, vlens, ao);
  gemm128_kernel<<<dim3(32, 8), 256, 0, stream>>>(ao, wot, nullptr, out, 2);
}

// Round 2
// 183.034 us; speedup vs baseline: 1.0460x; 1.0460x over previous
//
#include <hip/hip_runtime.h>
#include <stdint.h>

#define NH 16
#define SEQ 2048
#define DMODEL 1024
#define HD 64
#define NBATCH 2
#define MTOT (NBATCH * SEQ)              // 4096 rows for the big GEMMs
#define QSCALE 0.17677669529663687f      // 1/sqrt(B*H) = 1/sqrt(32)  (faithful bug)

typedef __bf16 bf16x8 __attribute__((ext_vector_type(8)));
typedef __bf16 bf16x4 __attribute__((ext_vector_type(4)));
typedef float f32x4 __attribute__((ext_vector_type(4)));

// round-to-nearest-even fp32 -> bf16 bit pattern
__device__ __forceinline__ unsigned short bf16u(float x) {
  unsigned u = __builtin_bit_cast(unsigned, x);
  u += 0x7fffu + ((u >> 16) & 1u);
  return (unsigned short)(u >> 16);
}

__device__ __forceinline__ f32x4 mfma16(bf16x8 a, bf16x8 b, f32x4 c) {
  return __builtin_amdgcn_mfma_f32_16x16x32_bf16(a, b, c, 0, 0, 0);
}

__device__ __forceinline__ void gl16(const void* g, void* l) {
  __builtin_amdgcn_global_load_lds(
      (const __attribute__((address_space(1))) void*)g,
      (__attribute__((address_space(3))) void*)l, 16, 0, 0);
}

// ---- cast fp32 -> bf16 for queries/keys/values (each 4096x1024) ----
__global__ __launch_bounds__(256) void cast_x_kernel(
    const float* __restrict__ x0, const float* __restrict__ x1,
    const float* __restrict__ x2, unsigned short* __restrict__ o0,
    unsigned short* __restrict__ o1, unsigned short* __restrict__ o2) {
  const float* src = (blockIdx.y == 0) ? x0 : (blockIdx.y == 1) ? x1 : x2;
  unsigned short* dst = (blockIdx.y == 0) ? o0 : (blockIdx.y == 1) ? o1 : o2;
  const int n4 = MTOT * DMODEL / 4;
  for (int i = blockIdx.x * blockDim.x + threadIdx.x; i < n4;
       i += gridDim.x * blockDim.x) {
    float4 f = reinterpret_cast<const float4*>(src)[i];
    ushort4 u;
    u.x = bf16u(f.x); u.y = bf16u(f.y); u.z = bf16u(f.z); u.w = bf16u(f.w);
    reinterpret_cast<ushort4*>(dst)[i] = u;
  }
}

// ---- transpose + cast W (1024x1024 fp32 stored (K,N)) -> Wt bf16 (N,K) ----
__global__ __launch_bounds__(256) void transpose_w_kernel(
    const float* __restrict__ w0, const float* __restrict__ w1,
    const float* __restrict__ w2, const float* __restrict__ w3,
    unsigned short* __restrict__ t0, unsigned short* __restrict__ t1,
    unsigned short* __restrict__ t2, unsigned short* __restrict__ t3) {
  __shared__ float tile[64][65];   // +1 pad: conflict-free column reads
  const float* w = (blockIdx.z == 0) ? w0 : (blockIdx.z == 1) ? w1
                   : (blockIdx.z == 2) ? w2 : w3;
  unsigned short* t = (blockIdx.z == 0) ? t0 : (blockIdx.z == 1) ? t1
                      : (blockIdx.z == 2) ? t2 : t3;
  int k0 = blockIdx.y * 64, n0 = blockIdx.x * 64;
  int tx = threadIdx.x & 63, ty = threadIdx.x >> 6;
#pragma unroll
  for (int i = 0; i < 16; ++i) {
    int kk = ty * 16 + i;
    tile[kk][tx] = w[(k0 + kk) * DMODEL + n0 + tx];   // coalesced read
  }
  __syncthreads();
#pragma unroll
  for (int i = 0; i < 16; ++i) {
    int nn = ty * 16 + i;
    t[(n0 + nn) * DMODEL + k0 + tx] = bf16u(tile[tx][nn]);  // coalesced write
  }
}

// ---- 128x128-tile bf16 GEMM body, K=1024, N=1024.  C = A(M,K) @ Wt(N,K)^T --
// mode 0: out bf16, head-split (B,H,S,hd)   (for q, k)
// mode 1: out bf16, head-split transposed (B,H,hd,S)  (for v)
// mode 2: out fp32, plain row-major (M,N)   (final projection)
__device__ __forceinline__ void gemm128_body(
    const unsigned short* __restrict__ A, const unsigned short* __restrict__ Wt,
    unsigned short* __restrict__ outb, float* __restrict__ outf, int mode,
    unsigned short* lA, unsigned short* lB, int bx, int by) {
  const int tid = threadIdx.x;
  const int lane = tid & 63, wid = tid >> 6;
  const int wr = wid >> 1, wc = wid & 1;
  const int m0 = bx * 128, n0 = by * 128;
  const int lm = lane & 15, lg = lane >> 4;
  const int lk = lg * 8;

  f32x4 acc[4][4] = {};

  for (int kt = 0; kt < DMODEL / 32; ++kt) {
#pragma unroll
    for (int i = 0; i < 2; ++i) {
      int c = tid + i * 256;                 // 0..511 16B chunks
      int row = c >> 2, cb = c & 3;
      gl16(A + (m0 + row) * DMODEL + kt * 32 + cb * 8, (char*)lA + c * 16);
      gl16(Wt + (n0 + row) * DMODEL + kt * 32 + cb * 8, (char*)lB + c * 16);
    }
    __syncthreads();   // drains vmcnt(0): staging complete

    bf16x8 af[4], bfr[4];
#pragma unroll
    for (int x = 0; x < 4; ++x) {
      af[x] = *reinterpret_cast<const bf16x8*>(&lA[(wr * 64 + x * 16 + lm) * 32 + lk]);
      bfr[x] = *reinterpret_cast<const bf16x8*>(&lB[(wc * 64 + x * 16 + lm) * 32 + lk]);
    }
#pragma unroll
    for (int mi = 0; mi < 4; ++mi)
#pragma unroll
      for (int ni = 0; ni < 4; ++ni)
        acc[mi][ni] = mfma16(af[mi], bfr[ni], acc[mi][ni]);
    __syncthreads();   // all reads done before next staging
  }

  // epilogue.  C/D layout: col = lane&15, row = (lane>>4)*4 + r
#pragma unroll
  for (int mi = 0; mi < 4; ++mi) {
#pragma unroll
    for (int ni = 0; ni < 4; ++ni) {
      int col = n0 + wc * 64 + ni * 16 + lm;
#pragma unroll
      for (int r = 0; r < 4; ++r) {
        int row = m0 + wr * 64 + mi * 16 + lg * 4 + r;
        float v = acc[mi][ni][r];
        if (mode == 2) {
          outf[row * DMODEL + col] = v;
        } else {
          int b = row >> 11, s = row & (SEQ - 1);
          int h = col >> 6, d = col & (HD - 1);
          int idx = (mode == 0) ? (((b * NH + h) * SEQ + s) * HD + d)
                                : (((b * NH + h) * HD + d) * SEQ + s);
          outb[idx] = bf16u(v);
        }
      }
    }
  }
}

// fused Q/K/V projections: z selects operand set (768 blocks ~ 3/CU)
__global__ __launch_bounds__(256) void gemm_qkv_kernel(
    const unsigned short* __restrict__ xq, const unsigned short* __restrict__ xk,
    const unsigned short* __restrict__ xv,
    const unsigned short* __restrict__ wq, const unsigned short* __restrict__ wk,
    const unsigned short* __restrict__ wv,
    unsigned short* __restrict__ qb, unsigned short* __restrict__ kb,
    unsigned short* __restrict__ vt) {
  __shared__ unsigned short lA[128 * 32];
  __shared__ unsigned short lB[128 * 32];
  const int z = blockIdx.z;
  const unsigned short* A = (z == 0) ? xq : (z == 1) ? xk : xv;
  const unsigned short* Wt = (z == 0) ? wq : (z == 1) ? wk : wv;
  unsigned short* outb = (z == 0) ? qb : (z == 1) ? kb : vt;
  gemm128_body(A, Wt, outb, nullptr, (z == 2) ? 1 : 0, lA, lB,
               blockIdx.x, blockIdx.y);
}

// final projection
__global__ __launch_bounds__(256) void gemm_out_kernel(
    const unsigned short* __restrict__ A, const unsigned short* __restrict__ Wt,
    float* __restrict__ outf) {
  __shared__ unsigned short lA[128 * 32];
  __shared__ unsigned short lB[128 * 32];
  gemm128_body(A, Wt, nullptr, outf, 2, lA, lB, blockIdx.x, blockIdx.y);
}

// ---- barrier-free flash attention, swapped QK^T ----
// qb, kb: (B,H,S,64) bf16;  vt: (B,H,64,S) bf16;  ao: (B,S,1024) bf16
// Each wave owns 16 q-rows (q = s0 + w*16 + lm); no __syncthreads anywhere.
__global__ __launch_bounds__(256) void attn2_kernel(
    const unsigned short* __restrict__ qb, const unsigned short* __restrict__ kb,
    const unsigned short* __restrict__ vt, const int* __restrict__ vlens,
    unsigned short* __restrict__ ao) {
  __shared__ unsigned short lP[4][16 * 64];   // per-wave P[q][key], swizzled
  const int tid = threadIdx.x;
  const int lane = tid & 63, w = tid >> 6;
  const int lm = lane & 15, lg = lane >> 4;
  const int bh = blockIdx.y, b = bh >> 4, h = bh & 15;
  const int s0 = blockIdx.x * 64;
  const int q = s0 + w * 16 + lm;
  const int vlen = vlens[b];
  const int nkt = (vlen + 63) >> 6;

  // Q fragments (B-operand: col=q=lm, k = d = lg*8..)
  const unsigned short* qrow = qb + (bh * SEQ + q) * HD;
  bf16x8 qf0 = *reinterpret_cast<const bf16x8*>(qrow + lg * 8);
  bf16x8 qf1 = *reinterpret_cast<const bf16x8*>(qrow + 32 + lg * 8);

  const unsigned short* kbase = kb + bh * SEQ * HD;
  const unsigned short* vbase = vt + (size_t)bh * HD * SEQ;
  char* pbuf = (char*)&lP[w][0];
  const int swz = (lm & 7) << 4;

  f32x4 oacc[4] = {};          // O^T: oacc[ndb][r] = O[q][ndb*16+lg*4+r]
  float m = -3e38f, l = 0.f;

  for (int kt = 0; kt < nkt; ++kt) {
    const int k0 = kt * 64;
    // S^T = K Q^T : sa[nb] -> S[q=lm][key = k0 + nb*16 + lg*4 + r]
    f32x4 sa[4];
#pragma unroll
    for (int nb = 0; nb < 4; ++nb) {
      const unsigned short* kr = kbase + (k0 + nb * 16 + lm) * HD;
      bf16x8 kf0 = *reinterpret_cast<const bf16x8*>(kr + lg * 8);
      bf16x8 kf1 = *reinterpret_cast<const bf16x8*>(kr + 32 + lg * 8);
      f32x4 z = {};
      z = mfma16(kf0, qf0, z);
      z = mfma16(kf1, qf1, z);
      sa[nb] = z;
    }

    const bool lastt = (kt == nkt - 1);
    float sc[4][4];
    float tmax = -3e38f;
#pragma unroll
    for (int nb = 0; nb < 4; ++nb)
#pragma unroll
      for (int r = 0; r < 4; ++r) {
        float x = sa[nb][r] * QSCALE;
        if (lastt && (k0 + nb * 16 + lg * 4 + r) >= vlen) x = -1000000.0f;
        sc[nb][r] = x;
        tmax = fmaxf(tmax, x);
      }
    tmax = fmaxf(tmax, __shfl_xor(tmax, 16, 64));
    tmax = fmaxf(tmax, __shfl_xor(tmax, 32, 64));
    float mn = fmaxf(m, tmax);
    float sf = __expf(m - mn);
    m = mn;

    float ps = 0.f;
    float pf[4][4];
#pragma unroll
    for (int nb = 0; nb < 4; ++nb)
#pragma unroll
      for (int r = 0; r < 4; ++r) {
        float p = __expf(sc[nb][r] - mn);
        pf[nb][r] = p;
        ps += p;
      }
    ps += __shfl_xor(ps, 16, 64);
    ps += __shfl_xor(ps, 32, 64);
    l = l * sf + ps;
#pragma unroll
    for (int ndb = 0; ndb < 4; ++ndb) oacc[ndb] *= sf;

    // write P[q=lm][key], per-wave LDS, XOR-swizzled rows (2-way max)
#pragma unroll
    for (int nb = 0; nb < 4; ++nb) {
      bf16x4 pk;
      pk[0] = (__bf16)pf[nb][0]; pk[1] = (__bf16)pf[nb][1];
      pk[2] = (__bf16)pf[nb][2]; pk[3] = (__bf16)pf[nb][3];
      int off = lm * 128 + (nb * 16 + lg * 4) * 2;
      *reinterpret_cast<bf16x4*>(pbuf + (off ^ swz)) = pk;
    }
    // (intra-wave LDS dep: compiler inserts lgkmcnt; DS ops in-order per wave)

    // O^T += V^T P^T over two 32-key chunks
#pragma unroll
    for (int c = 0; c < 2; ++c) {
      int roff = lm * 128 + c * 64 + lg * 16;
      bf16x8 pfc = *reinterpret_cast<const bf16x8*>(pbuf + (roff ^ swz));
#pragma unroll
      for (int ndb = 0; ndb < 4; ++ndb) {
        const unsigned short* vr =
            vbase + (ndb * 16 + lm) * SEQ + k0 + c * 32 + lg * 8;
        bf16x8 vf = *reinterpret_cast<const bf16x8*>(vr);
        oacc[ndb] = mfma16(vf, pfc, oacc[ndb]);
      }
    }
  }

  const float linv = 1.0f / l;
#pragma unroll
  for (int ndb = 0; ndb < 4; ++ndb) {
    ushort4 o;
    o.x = bf16u(oacc[ndb][0] * linv); o.y = bf16u(oacc[ndb][1] * linv);
    o.z = bf16u(oacc[ndb][2] * linv); o.w = bf16u(oacc[ndb][3] * linv);
    *reinterpret_cast<ushort4*>(
        ao + (b * SEQ + q) * DMODEL + h * HD + ndb * 16 + lg * 4) = o;
  }
}

extern "C" void kernel_launch(void* const* d_in, const int* in_sizes, int n_in,
                              void* d_out, int out_size, void* d_ws, size_t ws_size,
                              hipStream_t stream) {
  (void)in_sizes; (void)n_in; (void)out_size; (void)ws_size;
  const float* q = (const float*)d_in[0];
  const float* k = (const float*)d_in[1];
  const float* v = (const float*)d_in[2];
  const int* vlens = (const int*)d_in[3];
  const float* Wq = (const float*)d_in[4];
  const float* Wk = (const float*)d_in[5];
  const float* Wv = (const float*)d_in[6];
  const float* Wo = (const float*)d_in[7];
  float* out = (float*)d_out;

  char* ws = (char*)d_ws;
  const size_t MB = 1u << 20;
  unsigned short* xq = (unsigned short*)(ws + 0 * MB);   // 8 MB each
  unsigned short* xk = (unsigned short*)(ws + 8 * MB);
  unsigned short* xv = (unsigned short*)(ws + 16 * MB);
  unsigned short* wqt = (unsigned short*)(ws + 24 * MB); // 2 MB each
  unsigned short* wkt = (unsigned short*)(ws + 26 * MB);
  unsigned short* wvt = (unsigned short*)(ws + 28 * MB);
  unsigned short* wot = (unsigned short*)(ws + 30 * MB);
  unsigned short* qb = (unsigned short*)(ws + 32 * MB);  // 8 MB each
  unsigned short* kb = (unsigned short*)(ws + 40 * MB);
  unsigned short* vt = (unsigned short*)(ws + 48 * MB);
  unsigned short* ao = (unsigned short*)(ws + 56 * MB);

  cast_x_kernel<<<dim3(512, 3), 256, 0, stream>>>(q, k, v, xq, xk, xv);
  transpose_w_kernel<<<dim3(16, 16, 4), 256, 0, stream>>>(Wq, Wk, Wv, Wo,
                                                          wqt, wkt, wvt, wot);
  gemm_qkv_kernel<<<dim3(32, 8, 3), 256, 0, stream>>>(xq, xk, xv, wqt, wkt, wvt,
                                                      qb, kb, vt);
  attn2_kernel<<<dim3(SEQ / 64, NBATCH * NH), 256, 0, stream>>>(qb, kb, vt,
                                                                vlens, ao);
  gemm_out_kernel<<<dim3(32, 8), 256, 0, stream>>>(ao, wot, out);
}